// Round 2
// 128.703 us; speedup vs baseline: 1.0301x; 1.0301x over previous
//
#include <hip/hip_runtime.h>
#include <hip/hip_bf16.h>

typedef __attribute__((ext_vector_type(4))) float f32x4;
typedef __attribute__((ext_vector_type(8))) short bf16x8;
typedef __attribute__((ext_vector_type(4))) short short4v;

#define AROW 264  // shorts per A-LDS row: 64 j * 4 + 8 pad = 528 B (16B-aligned, odd quad-stride -> BW-floor b128 reads)
#define CS 516    // dwords per epilogue c row (512 + 4 pad -> 2-way max, free)

__device__ __forceinline__ short f2bf(float f) {
  __hip_bfloat16 h = __float2bfloat16(f);
  return __builtin_bit_cast(short, h);
}

// ---------------------------------------------------------------------------
// GEMM view: C[8192 x 512] = A[8192 x 1024] * B[1024 x 512], k = j*4 + kc,
// kc -> x component {0,1,2,4}.  512 cols = [c0 of i=0..255 | c4 of i=0..255].
// Bp (d_ws, 1 MB): per-lane MFMA B-fragment order Bp[it][cg][lane][8 shorts],
// cg = col/16. One frag load = 1 KB contiguous per wave (L2-hot).
// ---------------------------------------------------------------------------
__global__ __launch_bounds__(256) void ga_prep_B(const float* __restrict__ W,
                                                 short* __restrict__ Bp) {
  const int gid = blockIdx.x * 256 + threadIdx.x;  // 65536 = 32 it * 32 cg * 64 lane
  const int l  = gid & 63;
  const int cg = (gid >> 6) & 31;
  const int it = gid >> 11;
  const int ln = l & 15, q = l >> 4;
  const int hc = cg >> 4;                 // 0 -> c0 row, 1 -> c4 row
  const int i  = (cg & 15) * 16 + ln;
  const int j0 = it * 8 + q * 2;
  const float4* W4 = (const float4*)W;

  bf16x8 o;
#pragma unroll
  for (int jj = 0; jj < 2; ++jj) {
    const float4 wv = W4[((j0 + jj) * 256 + i) * 2];  // W[j][i][0..3]
    if (!hc) {
      o[jj * 4 + 0] = f2bf(wv.x); o[jj * 4 + 1] = f2bf(wv.y);
      o[jj * 4 + 2] = f2bf(wv.z); o[jj * 4 + 3] = 0;
    } else {
      o[jj * 4 + 0] = 0;           o[jj * 4 + 1] = f2bf(wv.z);
      o[jj * 4 + 2] = f2bf(-wv.y); o[jj * 4 + 3] = f2bf(wv.x);
    }
  }
  *(bf16x8*)&Bp[(size_t)gid * 8] = o;
}

// ---------------------------------------------------------------------------
// Main: 256 blocks (32 rows x ALL 512 cols) x 1024 threads (16 waves) ->
// 1 block/CU, 16 waves/CU (50% occ). Wave = 32 rows x 32 cols (2 cgs):
// each B frag feeds 2 MFMAs -> Bp L2 traffic halved vs 16-row tiling
// (512 MB -> 256 MB). B-frag reg pipeline depth 4 (issue-to-use ~3 iters
// x 4 waves/SIMD covers ~200cy L2 latency). K in 4 quarters of 256 (64 j):
// bulk-coalesced x slab -> regs -> shuffle comp4 -> bf16 -> A_lds
// (double-buffered), ONE barrier per quarter, NO global x access in K-loop.
// Epilogue: two 16-row passes through c_lds alias, nontemporal full-mv writes.
// ---------------------------------------------------------------------------
__global__ __launch_bounds__(1024, 4) void ga_mv_main(
    const float* __restrict__ x, const short* __restrict__ Bp,
    const float* __restrict__ bias, float* __restrict__ y) {
  __shared__ __align__(16) char smem[33792];
  short* Abuf[2] = {(short*)smem, (short*)(smem + 32 * AROW * 2)};
  float* c_lds = (float*)smem;  // epilogue alias (A dead by then): 16*516*4 = 33024

  const int t = threadIdx.x;
  const int bm = blockIdx.x;         // 256 blocks x 32 rows
  const int lane = t & 63, w = t >> 6;
  const int ln = lane & 15, qq = lane >> 4;
  const int R0 = bm * 32;

  // staging map: thread t, i=0..3 -> row = (t>>7)+8i, float4-col c4i = t&127
  //   c4i = j_local*2 + h  (h: 0 -> comps 0-3, 1 -> comps 4-7)
  const int ci = t & 127, rb = t >> 7;
  const int jl = ci >> 1, h2 = ci & 1;
  const float4* x4 = (const float4*)x;
  float4 fr[4];

#define LOADX(qtr)                                                           \
  {                                                                          \
    _Pragma("unroll")                                                        \
    for (int i = 0; i < 4; ++i)                                              \
      fr[i] = x4[(size_t)(R0 + rb + 8 * i) * 512 + (qtr) * 128 + ci];        \
  }

#define PROC(dst)                                                            \
  {                                                                          \
    _Pragma("unroll")                                                        \
    for (int i = 0; i < 4; ++i) {                                            \
      const float c4 = __shfl_xor(fr[i].x, 1, 64);                           \
      if (!h2) {                                                             \
        short4v a;                                                           \
        a[0] = f2bf(fr[i].x); a[1] = f2bf(fr[i].y);                          \
        a[2] = f2bf(fr[i].z); a[3] = f2bf(c4);                               \
        *(short4v*)&(dst)[(rb + 8 * i) * AROW + jl * 4] = a;                 \
      }                                                                      \
    }                                                                        \
  }

  // B frag pipeline (depth 4). Wave w owns cgs 2w, 2w+1 (cols w*32..w*32+31).
  const size_t bbase = (size_t)w * 1024 + lane * 8;
  bf16x8 Bf[4][2];
#define LB(itv, b)                                                           \
  {                                                                          \
    const short* p = Bp + (size_t)(itv) * 16384 + bbase;                     \
    Bf[b][0] = *(const bf16x8*)(p);                                          \
    Bf[b][1] = *(const bf16x8*)(p + 512);                                    \
  }

  // ---- prologue ----
  LOADX(0);
  PROC(Abuf[0]);
  __syncthreads();
  LB(0, 0);
  LB(1, 1);
  LB(2, 2);
  LB(3, 3);
  LOADX(1);  // in flight across quarter 0

  f32x4 acc[2][2] = {};

#pragma unroll
  for (int q = 0; q < 4; ++q) {
    const short* Ac = Abuf[q & 1];
#pragma unroll
    for (int tau = 0; tau < 8; ++tau) {
      const int it = q * 8 + tau;
      if (tau == 4 && q < 3) {
        PROC(Abuf[(q + 1) & 1]);       // waits the LOADX issued last quarter
        if (q < 2) LOADX(q + 2);       // refill fr for next quarter's PROC
      }
      const bf16x8 af0 = *(const bf16x8*)&Ac[ln * AROW + (tau * 8 + qq * 2) * 4];
      const bf16x8 af1 = *(const bf16x8*)&Ac[(16 + ln) * AROW + (tau * 8 + qq * 2) * 4];
#pragma unroll
      for (int n = 0; n < 2; ++n) {
        acc[0][n] = __builtin_amdgcn_mfma_f32_16x16x32_bf16(af0, Bf[it & 3][n],
                                                            acc[0][n], 0, 0, 0);
        acc[1][n] = __builtin_amdgcn_mfma_f32_16x16x32_bf16(af1, Bf[it & 3][n],
                                                            acc[1][n], 0, 0, 0);
      }
      if (it + 4 < 32) LB(it + 4, it & 3);  // after use of Bf[it&3] (WAR-safe)
    }
    __syncthreads();  // one barrier per quarter: A-buf swap guard
  }

  // ---- epilogue: two 16-row passes; acc[ep] -> c_lds -> full-mv y writes ----
  // C/D layout: col = ln, row(within 16-tile) = qq*4 + r
  const int h = t & 1, p = (t >> 1) & 255, rh = t >> 9;
  const float4 bv = ((const float4*)bias)[p * 2 + h];
  f32x4* y4 = (f32x4*)y;

#pragma unroll
  for (int ep = 0; ep < 2; ++ep) {
    if (ep) __syncthreads();  // pass-0 reads done before pass-1 writes
#pragma unroll
    for (int n = 0; n < 2; ++n)
#pragma unroll
      for (int r = 0; r < 4; ++r)
        c_lds[(qq * 4 + r) * CS + w * 32 + n * 16 + ln] = acc[ep][n][r];
    __syncthreads();
#pragma unroll
    for (int rr = 0; rr < 8; ++rr) {
      const int row = rr * 2 + rh;
      f32x4 o;
      o[0] = bv.x; o[1] = bv.y; o[2] = bv.z; o[3] = bv.w;
      o[0] += c_lds[row * CS + h * 256 + p];  // +c0 into comp0 / +c4 into comp4
      __builtin_nontemporal_store(
          o, &y4[((size_t)(R0 + ep * 16 + row) * 256 + p) * 2 + h]);
    }
  }
}

extern "C" void kernel_launch(void* const* d_in, const int* in_sizes, int n_in,
                              void* d_out, int out_size, void* d_ws, size_t ws_size,
                              hipStream_t stream) {
  const float* x = (const float*)d_in[0];
  const float* W = (const float*)d_in[1];
  const float* bias = (const float*)d_in[2];
  float* y = (float*)d_out;
  short* Bp = (short*)d_ws;  // 32*32*64*16 = 1,048,576 B

  ga_prep_B<<<dim3(256), dim3(256), 0, stream>>>(W, Bp);
  ga_mv_main<<<dim3(256), dim3(1024), 0, stream>>>(x, Bp, bias, y);
}

// Round 3
// 127.313 us; speedup vs baseline: 1.0414x; 1.0109x over previous
//
#include <hip/hip_runtime.h>
#include <hip/hip_bf16.h>

typedef __attribute__((ext_vector_type(4))) float f32x4;
typedef __attribute__((ext_vector_type(8))) short bf16x8;
typedef __attribute__((ext_vector_type(4))) short short4v;

#define AROW 264  // shorts per A-LDS row: 64 j * 4 + 8 pad = 528 B (16B-aligned, odd quad-stride -> BW-floor b128 reads)
#define CS 516    // dwords per epilogue c row (512 + 4 pad -> 2-way max, free)

__device__ __forceinline__ short f2bf(float f) {
  __hip_bfloat16 h = __float2bfloat16(f);
  return __builtin_bit_cast(short, h);
}

// Raw quarter barrier: complete MY lds reads+writes (lgkmcnt counts both),
// then s_barrier. NO vmcnt drain -> x-load + B-frag + y-store pipelines
// survive the barrier (removes the 4x full s_waitcnt vmcnt(0) drains that
// __syncthreads emits). sched_barrier(0) pins LDS ops on the correct side.
#define QBAR()                                            \
  {                                                       \
    asm volatile("s_waitcnt lgkmcnt(0)" ::: "memory");    \
    __builtin_amdgcn_sched_barrier(0);                    \
    __builtin_amdgcn_s_barrier();                         \
    __builtin_amdgcn_sched_barrier(0);                    \
  }

// ---------------------------------------------------------------------------
// GEMM view: C[8192 x 512] = A[8192 x 1024] * B[1024 x 512], k = j*4 + kc,
// kc -> x component {0,1,2,4}.  512 cols = [c0 of i=0..255 | c4 of i=0..255].
// Bp (d_ws, 1 MB): per-lane MFMA B-fragment order Bp[it][cg][lane][8 shorts],
// cg = col/16. One frag load = 1 KB contiguous per wave (L2-hot).
// ---------------------------------------------------------------------------
__global__ __launch_bounds__(256) void ga_prep_B(const float* __restrict__ W,
                                                 short* __restrict__ Bp) {
  const int gid = blockIdx.x * 256 + threadIdx.x;  // 65536 = 32 it * 32 cg * 64 lane
  const int l  = gid & 63;
  const int cg = (gid >> 6) & 31;
  const int it = gid >> 11;
  const int ln = l & 15, q = l >> 4;
  const int hc = cg >> 4;                 // 0 -> c0 row, 1 -> c4 row
  const int i  = (cg & 15) * 16 + ln;
  const int j0 = it * 8 + q * 2;
  const float4* W4 = (const float4*)W;

  bf16x8 o;
#pragma unroll
  for (int jj = 0; jj < 2; ++jj) {
    const float4 wv = W4[((j0 + jj) * 256 + i) * 2];  // W[j][i][0..3]
    if (!hc) {
      o[jj * 4 + 0] = f2bf(wv.x); o[jj * 4 + 1] = f2bf(wv.y);
      o[jj * 4 + 2] = f2bf(wv.z); o[jj * 4 + 3] = 0;
    } else {
      o[jj * 4 + 0] = 0;           o[jj * 4 + 1] = f2bf(wv.z);
      o[jj * 4 + 2] = f2bf(-wv.y); o[jj * 4 + 3] = f2bf(wv.x);
    }
  }
  *(bf16x8*)&Bp[(size_t)gid * 8] = o;
}

// ---------------------------------------------------------------------------
// Main: 256 blocks (32 rows x ALL 512 cols) x 1024 threads (16 waves).
// Wave = 32 rows x 32 cols (2 cgs). B-frag reg pipeline depth 4. K in 4
// quarters of 256 (64 j): bulk-coalesced x slab -> regs -> shuffle comp4 ->
// bf16 -> A_lds (double-buffered). ONE raw barrier per quarter (lgkm-only:
// vmcnt pipelines cross it). Epilogue: two 16-row passes via c_lds alias,
// nontemporal full-mv writes.
// ---------------------------------------------------------------------------
__global__ __launch_bounds__(1024, 4) void ga_mv_main(
    const float* __restrict__ x, const short* __restrict__ Bp,
    const float* __restrict__ bias, float* __restrict__ y) {
  __shared__ __align__(16) char smem[33792];
  short* Abuf[2] = {(short*)smem, (short*)(smem + 32 * AROW * 2)};
  float* c_lds = (float*)smem;  // epilogue alias (A dead by then): 16*516*4 = 33024

  const int t = threadIdx.x;
  const int bm = blockIdx.x;         // 256 blocks x 32 rows
  const int lane = t & 63, w = t >> 6;
  const int ln = lane & 15, qq = lane >> 4;
  const int R0 = bm * 32;

  // staging map: thread t, i=0..3 -> row = (t>>7)+8i, float4-col c4i = t&127
  //   c4i = j_local*2 + h  (h: 0 -> comps 0-3, 1 -> comps 4-7)
  const int ci = t & 127, rb = t >> 7;
  const int jl = ci >> 1, h2 = ci & 1;
  const float4* x4 = (const float4*)x;
  float4 fr[4];

#define LOADX(qtr)                                                           \
  {                                                                          \
    _Pragma("unroll")                                                        \
    for (int i = 0; i < 4; ++i)                                              \
      fr[i] = x4[(size_t)(R0 + rb + 8 * i) * 512 + (qtr) * 128 + ci];        \
  }

#define PROC(dst)                                                            \
  {                                                                          \
    _Pragma("unroll")                                                        \
    for (int i = 0; i < 4; ++i) {                                            \
      const float c4 = __shfl_xor(fr[i].x, 1, 64);                           \
      if (!h2) {                                                             \
        short4v a;                                                           \
        a[0] = f2bf(fr[i].x); a[1] = f2bf(fr[i].y);                          \
        a[2] = f2bf(fr[i].z); a[3] = f2bf(c4);                               \
        *(short4v*)&(dst)[(rb + 8 * i) * AROW + jl * 4] = a;                 \
      }                                                                      \
    }                                                                        \
  }

  // B frag pipeline (depth 4). Wave w owns cgs 2w, 2w+1 (cols w*32..w*32+31).
  const size_t bbase = (size_t)w * 1024 + lane * 8;
  bf16x8 Bf[4][2];
#define LB(itv, b)                                                           \
  {                                                                          \
    const short* p = Bp + (size_t)(itv) * 16384 + bbase;                     \
    Bf[b][0] = *(const bf16x8*)(p);                                          \
    Bf[b][1] = *(const bf16x8*)(p + 512);                                    \
  }

  // ---- prologue ----
  LOADX(0);
  PROC(Abuf[0]);
  __syncthreads();
  LB(0, 0);
  LB(1, 1);
  LB(2, 2);
  LB(3, 3);
  LOADX(1);  // in flight across quarter 0

  f32x4 acc[2][2] = {};

#pragma unroll
  for (int q = 0; q < 4; ++q) {
    const short* Ac = Abuf[q & 1];
#pragma unroll
    for (int tau = 0; tau < 8; ++tau) {
      const int it = q * 8 + tau;
      if (tau == 4 && q < 3) {
        PROC(Abuf[(q + 1) & 1]);       // waits the LOADX issued last quarter
        if (q < 2) LOADX(q + 2);       // refill fr for next quarter's PROC
      }
      const bf16x8 af0 = *(const bf16x8*)&Ac[ln * AROW + (tau * 8 + qq * 2) * 4];
      const bf16x8 af1 = *(const bf16x8*)&Ac[(16 + ln) * AROW + (tau * 8 + qq * 2) * 4];
#pragma unroll
      for (int n = 0; n < 2; ++n) {
        acc[0][n] = __builtin_amdgcn_mfma_f32_16x16x32_bf16(af0, Bf[it & 3][n],
                                                            acc[0][n], 0, 0, 0);
        acc[1][n] = __builtin_amdgcn_mfma_f32_16x16x32_bf16(af1, Bf[it & 3][n],
                                                            acc[1][n], 0, 0, 0);
      }
      if (it + 4 < 32) LB(it + 4, it & 3);  // after use of Bf[it&3] (WAR-safe)
    }
    QBAR();  // A-buf swap guard: lgkm-complete + s_barrier, NO vmcnt drain
  }

  // ---- epilogue: two 16-row passes; acc[ep] -> c_lds -> full-mv y writes ----
  // C/D layout: col = ln, row(within 16-tile) = qq*4 + r
  const int h = t & 1, p = (t >> 1) & 255, rh = t >> 9;
  const float4 bv = ((const float4*)bias)[p * 2 + h];
  f32x4* y4 = (f32x4*)y;

#pragma unroll
  for (int ep = 0; ep < 2; ++ep) {
    if (ep) __syncthreads();  // pass-0 reads done before pass-1 writes
#pragma unroll
    for (int n = 0; n < 2; ++n)
#pragma unroll
      for (int r = 0; r < 4; ++r)
        c_lds[(qq * 4 + r) * CS + w * 32 + n * 16 + ln] = acc[ep][n][r];
    __syncthreads();
#pragma unroll
    for (int rr = 0; rr < 8; ++rr) {
      const int row = rr * 2 + rh;
      f32x4 o;
      o[0] = bv.x; o[1] = bv.y; o[2] = bv.z; o[3] = bv.w;
      o[0] += c_lds[row * CS + h * 256 + p];  // +c0 into comp0 / +c4 into comp4
      __builtin_nontemporal_store(
          o, &y4[((size_t)(R0 + ep * 16 + row) * 256 + p) * 2 + h]);
    }
  }
}

extern "C" void kernel_launch(void* const* d_in, const int* in_sizes, int n_in,
                              void* d_out, int out_size, void* d_ws, size_t ws_size,
                              hipStream_t stream) {
  const float* x = (const float*)d_in[0];
  const float* W = (const float*)d_in[1];
  const float* bias = (const float*)d_in[2];
  float* y = (float*)d_out;
  short* Bp = (short*)d_ws;  // 32*32*64*16 = 1,048,576 B

  ga_prep_B<<<dim3(256), dim3(256), 0, stream>>>(W, Bp);
  ga_mv_main<<<dim3(256), dim3(1024), 0, stream>>>(x, Bp, bias, y);
}